// Round 1
// baseline (140.340 us; speedup 1.0000x reference)
//
#include <hip/hip_runtime.h>

#define BATCH   8
#define SEQLEN  2048
#define DMODEL  1024
#define DSTATE  16
#define NCHUNK  16
#define TCHUNK  (SEQLEN / NCHUNK)   // 128
#define BLOCK   256
#define LOG2E   1.4426950408889634f

// ---------------------------------------------------------------------------
// Phase A: per-(b,d,chunk) local scan starting from h = 0.
// Emits h_loc[16] and dsum (sum of delta over chunk) to workspace.
// Chunk aggregate decay is exp(A[n] * dsum) because A is diagonal.
// ---------------------------------------------------------------------------
__global__ __launch_bounds__(BLOCK) void ssm_phaseA(
    const float* __restrict__ u,  const float* __restrict__ de,
    const float* __restrict__ A,  const float* __restrict__ Bm,
    float* __restrict__ ws_h, float* __restrict__ ws_d)
{
    __shared__ float sB[TCHUNK * DSTATE];   // 8 KB
    const int tid = threadIdx.x;
    const int d   = blockIdx.x * BLOCK + tid;
    const int c   = blockIdx.y;
    const int b   = blockIdx.z;
    const int t0  = c * TCHUNK;

    // stage B tile (same for all d in block): fully coalesced
    {
        const float4* src = (const float4*)(Bm + (size_t)(b * SEQLEN + t0) * DSTATE);
        float4* dst = (float4*)sB;
        #pragma unroll
        for (int i = 0; i < (TCHUNK * DSTATE / 4) / BLOCK; ++i)
            dst[tid + i * BLOCK] = src[tid + i * BLOCK];
    }
    __syncthreads();

    float A2[DSTATE];
    #pragma unroll
    for (int n = 0; n < DSTATE; n += 4) {
        float4 a4 = *(const float4*)(A + (size_t)d * DSTATE + n);
        A2[n+0] = a4.x * LOG2E; A2[n+1] = a4.y * LOG2E;
        A2[n+2] = a4.z * LOG2E; A2[n+3] = a4.w * LOG2E;
    }
    float h[DSTATE];
    #pragma unroll
    for (int n = 0; n < DSTATE; ++n) h[n] = 0.f;
    float dsum = 0.f;

    const float* up = u  + (size_t)(b * SEQLEN + t0) * DMODEL + d;
    const float* dp = de + (size_t)(b * SEQLEN + t0) * DMODEL + d;

    for (int t = 0; t < TCHUNK; ++t) {
        float dl = dp[(size_t)t * DMODEL];
        float uu = up[(size_t)t * DMODEL];
        dsum += dl;
        float du = dl * uu;
        #pragma unroll
        for (int n = 0; n < DSTATE; n += 4) {
            float4 b4 = *(const float4*)(sB + t * DSTATE + n);
            h[n+0] = __builtin_amdgcn_exp2f(dl * A2[n+0]) * h[n+0] + du * b4.x;
            h[n+1] = __builtin_amdgcn_exp2f(dl * A2[n+1]) * h[n+1] + du * b4.y;
            h[n+2] = __builtin_amdgcn_exp2f(dl * A2[n+2]) * h[n+2] + du * b4.z;
            h[n+3] = __builtin_amdgcn_exp2f(dl * A2[n+3]) * h[n+3] + du * b4.w;
        }
    }

    float* wh = ws_h + (size_t)(b * NCHUNK + c) * DSTATE * DMODEL + d;
    #pragma unroll
    for (int n = 0; n < DSTATE; ++n) wh[(size_t)n * DMODEL] = h[n];
    ws_d[(size_t)(b * NCHUNK + c) * DMODEL + d] = dsum;
}

// ---------------------------------------------------------------------------
// Phase C: combine predecessor chunk aggregates (cheap prologue), then
// recompute the chunk scan with the correct incoming state and write y.
// ---------------------------------------------------------------------------
__global__ __launch_bounds__(BLOCK) void ssm_phaseC(
    const float* __restrict__ u,  const float* __restrict__ de,
    const float* __restrict__ A,  const float* __restrict__ Bm,
    const float* __restrict__ Cm, const float* __restrict__ Dv,
    const float* __restrict__ ws_h, const float* __restrict__ ws_d,
    float* __restrict__ y)
{
    __shared__ float sB[TCHUNK * DSTATE];   // 8 KB
    __shared__ float sC[TCHUNK * DSTATE];   // 8 KB
    const int tid = threadIdx.x;
    const int d   = blockIdx.x * BLOCK + tid;
    const int c   = blockIdx.y;
    const int b   = blockIdx.z;
    const int t0  = c * TCHUNK;

    {
        const float4* srcB = (const float4*)(Bm + (size_t)(b * SEQLEN + t0) * DSTATE);
        const float4* srcC = (const float4*)(Cm + (size_t)(b * SEQLEN + t0) * DSTATE);
        float4* dstB = (float4*)sB;
        float4* dstC = (float4*)sC;
        #pragma unroll
        for (int i = 0; i < (TCHUNK * DSTATE / 4) / BLOCK; ++i) {
            dstB[tid + i * BLOCK] = srcB[tid + i * BLOCK];
            dstC[tid + i * BLOCK] = srcC[tid + i * BLOCK];
        }
    }
    __syncthreads();

    float A2[DSTATE];
    #pragma unroll
    for (int n = 0; n < DSTATE; n += 4) {
        float4 a4 = *(const float4*)(A + (size_t)d * DSTATE + n);
        A2[n+0] = a4.x * LOG2E; A2[n+1] = a4.y * LOG2E;
        A2[n+2] = a4.z * LOG2E; A2[n+3] = a4.w * LOG2E;
    }

    // combine predecessor chunk aggregates: H = decay_j * H + hloc_j
    float h[DSTATE];
    #pragma unroll
    for (int n = 0; n < DSTATE; ++n) h[n] = 0.f;
    for (int j = 0; j < c; ++j) {
        float dsj = ws_d[(size_t)(b * NCHUNK + j) * DMODEL + d];
        const float* wh = ws_h + (size_t)(b * NCHUNK + j) * DSTATE * DMODEL + d;
        #pragma unroll
        for (int n = 0; n < DSTATE; ++n)
            h[n] = __builtin_amdgcn_exp2f(A2[n] * dsj) * h[n] + wh[(size_t)n * DMODEL];
    }

    const float Dd = Dv[d];
    const float* up = u  + (size_t)(b * SEQLEN + t0) * DMODEL + d;
    const float* dp = de + (size_t)(b * SEQLEN + t0) * DMODEL + d;
    float* yp = y + (size_t)(b * SEQLEN + t0) * DMODEL + d;

    for (int t = 0; t < TCHUNK; ++t) {
        float dl = dp[(size_t)t * DMODEL];
        float uu = up[(size_t)t * DMODEL];
        float du  = dl * uu;
        float acc = Dd * uu;
        #pragma unroll
        for (int n = 0; n < DSTATE; n += 4) {
            float4 b4 = *(const float4*)(sB + t * DSTATE + n);
            float4 c4 = *(const float4*)(sC + t * DSTATE + n);
            h[n+0] = __builtin_amdgcn_exp2f(dl * A2[n+0]) * h[n+0] + du * b4.x;
            h[n+1] = __builtin_amdgcn_exp2f(dl * A2[n+1]) * h[n+1] + du * b4.y;
            h[n+2] = __builtin_amdgcn_exp2f(dl * A2[n+2]) * h[n+2] + du * b4.z;
            h[n+3] = __builtin_amdgcn_exp2f(dl * A2[n+3]) * h[n+3] + du * b4.w;
            acc += h[n+0] * c4.x;
            acc += h[n+1] * c4.y;
            acc += h[n+2] * c4.z;
            acc += h[n+3] * c4.w;
        }
        yp[(size_t)t * DMODEL] = acc;
    }
}

// ---------------------------------------------------------------------------
// Fallback (only if workspace is unexpectedly small): 1 thread per (b,d),
// full sequential scan. Correct but slow.
// ---------------------------------------------------------------------------
__global__ __launch_bounds__(BLOCK) void ssm_naive(
    const float* __restrict__ u,  const float* __restrict__ de,
    const float* __restrict__ A,  const float* __restrict__ Bm,
    const float* __restrict__ Cm, const float* __restrict__ Dv,
    float* __restrict__ y)
{
    const int tid = threadIdx.x;
    const int d   = blockIdx.x * BLOCK + tid;
    const int b   = blockIdx.z;

    float A2[DSTATE];
    #pragma unroll
    for (int n = 0; n < DSTATE; n += 4) {
        float4 a4 = *(const float4*)(A + (size_t)d * DSTATE + n);
        A2[n+0] = a4.x * LOG2E; A2[n+1] = a4.y * LOG2E;
        A2[n+2] = a4.z * LOG2E; A2[n+3] = a4.w * LOG2E;
    }
    float h[DSTATE];
    #pragma unroll
    for (int n = 0; n < DSTATE; ++n) h[n] = 0.f;
    const float Dd = Dv[d];

    const float* up = u  + (size_t)b * SEQLEN * DMODEL + d;
    const float* dp = de + (size_t)b * SEQLEN * DMODEL + d;
    float* yp = y + (size_t)b * SEQLEN * DMODEL + d;

    for (int t = 0; t < SEQLEN; ++t) {
        float dl = dp[(size_t)t * DMODEL];
        float uu = up[(size_t)t * DMODEL];
        float du  = dl * uu;
        float acc = Dd * uu;
        const float* bp = Bm + (size_t)(b * SEQLEN + t) * DSTATE;
        const float* cp = Cm + (size_t)(b * SEQLEN + t) * DSTATE;
        #pragma unroll
        for (int n = 0; n < DSTATE; n += 4) {
            float4 b4 = *(const float4*)(bp + n);
            float4 c4 = *(const float4*)(cp + n);
            h[n+0] = __builtin_amdgcn_exp2f(dl * A2[n+0]) * h[n+0] + du * b4.x;
            h[n+1] = __builtin_amdgcn_exp2f(dl * A2[n+1]) * h[n+1] + du * b4.y;
            h[n+2] = __builtin_amdgcn_exp2f(dl * A2[n+2]) * h[n+2] + du * b4.z;
            h[n+3] = __builtin_amdgcn_exp2f(dl * A2[n+3]) * h[n+3] + du * b4.w;
            acc += h[n+0] * c4.x;
            acc += h[n+1] * c4.y;
            acc += h[n+2] * c4.z;
            acc += h[n+3] * c4.w;
        }
        yp[(size_t)t * DMODEL] = acc;
    }
}

extern "C" void kernel_launch(void* const* d_in, const int* in_sizes, int n_in,
                              void* d_out, int out_size, void* d_ws, size_t ws_size,
                              hipStream_t stream) {
    const float* u  = (const float*)d_in[0];
    const float* de = (const float*)d_in[1];
    const float* A  = (const float*)d_in[2];
    const float* Bm = (const float*)d_in[3];
    const float* Cm = (const float*)d_in[4];
    const float* Dv = (const float*)d_in[5];
    float* y = (float*)d_out;

    const size_t n_wsh = (size_t)BATCH * NCHUNK * DSTATE * DMODEL;
    const size_t n_wsd = (size_t)BATCH * NCHUNK * DMODEL;
    const size_t need  = (n_wsh + n_wsd) * sizeof(float);

    if (ws_size >= need) {
        float* ws_h = (float*)d_ws;
        float* ws_d = ws_h + n_wsh;
        dim3 grid(DMODEL / BLOCK, NCHUNK, BATCH);
        ssm_phaseA<<<grid, BLOCK, 0, stream>>>(u, de, A, Bm, ws_h, ws_d);
        ssm_phaseC<<<grid, BLOCK, 0, stream>>>(u, de, A, Bm, Cm, Dv, ws_h, ws_d, y);
    } else {
        dim3 grid(DMODEL / BLOCK, 1, BATCH);
        ssm_naive<<<grid, BLOCK, 0, stream>>>(u, de, A, Bm, Cm, Dv, y);
    }
}

// Round 2
// 116.374 us; speedup vs baseline: 1.2059x; 1.2059x over previous
//
#include <hip/hip_runtime.h>

#define BATCH   8
#define SEQLEN  2048
#define DMODEL  1024
#define DSTATE  16
#define BLOCK   256
#define LOG2E   1.4426950408889634f

// ---------------------------------------------------------------------------
// Phase A: per-(b,d,chunk) local scan starting from h = 0.
// Emits h_loc[16] and dsum (sum of delta over chunk) to workspace.
// Chunk aggregate decay is exp(A[n] * dsum) because A is diagonal.
// ---------------------------------------------------------------------------
template<int NC>
__global__ __launch_bounds__(BLOCK) void ssm_phaseA(
    const float* __restrict__ u,  const float* __restrict__ de,
    const float* __restrict__ A,  const float* __restrict__ Bm,
    float* __restrict__ ws_h, float* __restrict__ ws_d)
{
    constexpr int TC = SEQLEN / NC;
    __shared__ float sB[TC * DSTATE];
    const int tid = threadIdx.x;
    const int d   = blockIdx.x * BLOCK + tid;
    const int c   = blockIdx.y;
    const int b   = blockIdx.z;
    const int t0  = c * TC;

    // stage B tile (same for all d in block): fully coalesced
    {
        const float4* src = (const float4*)(Bm + (size_t)(b * SEQLEN + t0) * DSTATE);
        float4* dst = (float4*)sB;
        for (int i = tid; i < TC * DSTATE / 4; i += BLOCK)
            dst[i] = src[i];
    }
    __syncthreads();

    float A2[DSTATE];
    #pragma unroll
    for (int n = 0; n < DSTATE; n += 4) {
        float4 a4 = *(const float4*)(A + (size_t)d * DSTATE + n);
        A2[n+0] = a4.x * LOG2E; A2[n+1] = a4.y * LOG2E;
        A2[n+2] = a4.z * LOG2E; A2[n+3] = a4.w * LOG2E;
    }
    float h[DSTATE];
    #pragma unroll
    for (int n = 0; n < DSTATE; ++n) h[n] = 0.f;
    float dsum = 0.f;

    const float* up = u  + (size_t)(b * SEQLEN + t0) * DMODEL + d;
    const float* dp = de + (size_t)(b * SEQLEN + t0) * DMODEL + d;

    #pragma unroll 2
    for (int t = 0; t < TC; ++t) {
        float dl = dp[(size_t)t * DMODEL];
        float uu = up[(size_t)t * DMODEL];
        dsum += dl;
        float du = dl * uu;
        #pragma unroll
        for (int n = 0; n < DSTATE; n += 4) {
            float4 b4 = *(const float4*)(sB + t * DSTATE + n);
            h[n+0] = __builtin_amdgcn_exp2f(dl * A2[n+0]) * h[n+0] + du * b4.x;
            h[n+1] = __builtin_amdgcn_exp2f(dl * A2[n+1]) * h[n+1] + du * b4.y;
            h[n+2] = __builtin_amdgcn_exp2f(dl * A2[n+2]) * h[n+2] + du * b4.z;
            h[n+3] = __builtin_amdgcn_exp2f(dl * A2[n+3]) * h[n+3] + du * b4.w;
        }
    }

    float* wh = ws_h + (size_t)(b * NC + c) * DSTATE * DMODEL + d;
    #pragma unroll
    for (int n = 0; n < DSTATE; ++n) wh[(size_t)n * DMODEL] = h[n];
    ws_d[(size_t)(b * NC + c) * DMODEL + d] = dsum;
}

// ---------------------------------------------------------------------------
// Phase B: inter-chunk exclusive prefix scan, in place.
// One thread per (b, n, d) strand; NC sequential steps each.
//   h_in[c] = sum_{j<c} decay(j..c) * h_loc[j]   (written over ws_h[c])
// ---------------------------------------------------------------------------
template<int NC>
__global__ __launch_bounds__(BLOCK) void ssm_phaseB(
    const float* __restrict__ A,
    float* __restrict__ ws_h, const float* __restrict__ ws_d)
{
    const int gid = blockIdx.x * BLOCK + threadIdx.x;   // (b, n, d)
    const int d  = gid % DMODEL;
    const int bn = gid / DMODEL;
    const int n  = bn % DSTATE;
    const int b  = bn / DSTATE;

    const float a2 = A[(size_t)d * DSTATE + n] * LOG2E;
    float h = 0.f;
    size_t ih = (size_t)b * NC * DSTATE * DMODEL + (size_t)n * DMODEL + d;
    size_t id = (size_t)b * NC * DMODEL + d;

    #pragma unroll 4
    for (int c = 0; c < NC; ++c) {
        float hl = ws_h[ih];
        float ds = ws_d[id];
        ws_h[ih] = h;                       // exclusive prefix
        h = __builtin_amdgcn_exp2f(a2 * ds) * h + hl;
        ih += (size_t)DSTATE * DMODEL;
        id += DMODEL;
    }
}

// ---------------------------------------------------------------------------
// Phase C: load incoming state, re-scan the chunk, write y.
// ---------------------------------------------------------------------------
template<int NC>
__global__ __launch_bounds__(BLOCK) void ssm_phaseC(
    const float* __restrict__ u,  const float* __restrict__ de,
    const float* __restrict__ A,  const float* __restrict__ Bm,
    const float* __restrict__ Cm, const float* __restrict__ Dv,
    const float* __restrict__ ws_h, float* __restrict__ y)
{
    constexpr int TC = SEQLEN / NC;
    __shared__ float sB[TC * DSTATE];
    __shared__ float sC[TC * DSTATE];
    const int tid = threadIdx.x;
    const int d   = blockIdx.x * BLOCK + tid;
    const int c   = blockIdx.y;
    const int b   = blockIdx.z;
    const int t0  = c * TC;

    {
        const float4* srcB = (const float4*)(Bm + (size_t)(b * SEQLEN + t0) * DSTATE);
        const float4* srcC = (const float4*)(Cm + (size_t)(b * SEQLEN + t0) * DSTATE);
        float4* dstB = (float4*)sB;
        float4* dstC = (float4*)sC;
        for (int i = tid; i < TC * DSTATE / 4; i += BLOCK) {
            dstB[i] = srcB[i];
            dstC[i] = srcC[i];
        }
    }
    __syncthreads();

    float A2[DSTATE];
    #pragma unroll
    for (int n = 0; n < DSTATE; n += 4) {
        float4 a4 = *(const float4*)(A + (size_t)d * DSTATE + n);
        A2[n+0] = a4.x * LOG2E; A2[n+1] = a4.y * LOG2E;
        A2[n+2] = a4.z * LOG2E; A2[n+3] = a4.w * LOG2E;
    }

    // incoming state from phase B (coalesced)
    float h[DSTATE];
    {
        const float* wh = ws_h + (size_t)(b * NC + c) * DSTATE * DMODEL + d;
        #pragma unroll
        for (int n = 0; n < DSTATE; ++n) h[n] = wh[(size_t)n * DMODEL];
    }

    const float Dd = Dv[d];
    const float* up = u  + (size_t)(b * SEQLEN + t0) * DMODEL + d;
    const float* dp = de + (size_t)(b * SEQLEN + t0) * DMODEL + d;
    float* yp = y + (size_t)(b * SEQLEN + t0) * DMODEL + d;

    #pragma unroll 2
    for (int t = 0; t < TC; ++t) {
        float dl = dp[(size_t)t * DMODEL];
        float uu = up[(size_t)t * DMODEL];
        float du  = dl * uu;
        float acc = Dd * uu;
        #pragma unroll
        for (int n = 0; n < DSTATE; n += 4) {
            float4 b4 = *(const float4*)(sB + t * DSTATE + n);
            float4 c4 = *(const float4*)(sC + t * DSTATE + n);
            h[n+0] = __builtin_amdgcn_exp2f(dl * A2[n+0]) * h[n+0] + du * b4.x;
            h[n+1] = __builtin_amdgcn_exp2f(dl * A2[n+1]) * h[n+1] + du * b4.y;
            h[n+2] = __builtin_amdgcn_exp2f(dl * A2[n+2]) * h[n+2] + du * b4.z;
            h[n+3] = __builtin_amdgcn_exp2f(dl * A2[n+3]) * h[n+3] + du * b4.w;
            acc += h[n+0] * c4.x;
            acc += h[n+1] * c4.y;
            acc += h[n+2] * c4.z;
            acc += h[n+3] * c4.w;
        }
        yp[(size_t)t * DMODEL] = acc;
    }
}

// ---------------------------------------------------------------------------
// Fallback: 1 thread per (b,d), full sequential scan. Correct but slow.
// ---------------------------------------------------------------------------
__global__ __launch_bounds__(BLOCK) void ssm_naive(
    const float* __restrict__ u,  const float* __restrict__ de,
    const float* __restrict__ A,  const float* __restrict__ Bm,
    const float* __restrict__ Cm, const float* __restrict__ Dv,
    float* __restrict__ y)
{
    const int tid = threadIdx.x;
    const int d   = blockIdx.x * BLOCK + tid;
    const int b   = blockIdx.z;

    float A2[DSTATE];
    #pragma unroll
    for (int n = 0; n < DSTATE; n += 4) {
        float4 a4 = *(const float4*)(A + (size_t)d * DSTATE + n);
        A2[n+0] = a4.x * LOG2E; A2[n+1] = a4.y * LOG2E;
        A2[n+2] = a4.z * LOG2E; A2[n+3] = a4.w * LOG2E;
    }
    float h[DSTATE];
    #pragma unroll
    for (int n = 0; n < DSTATE; ++n) h[n] = 0.f;
    const float Dd = Dv[d];

    const float* up = u  + (size_t)b * SEQLEN * DMODEL + d;
    const float* dp = de + (size_t)b * SEQLEN * DMODEL + d;
    float* yp = y + (size_t)b * SEQLEN * DMODEL + d;

    for (int t = 0; t < SEQLEN; ++t) {
        float dl = dp[(size_t)t * DMODEL];
        float uu = up[(size_t)t * DMODEL];
        float du  = dl * uu;
        float acc = Dd * uu;
        const float* bp = Bm + (size_t)(b * SEQLEN + t) * DSTATE;
        const float* cp = Cm + (size_t)(b * SEQLEN + t) * DSTATE;
        #pragma unroll
        for (int n = 0; n < DSTATE; n += 4) {
            float4 b4 = *(const float4*)(bp + n);
            float4 c4 = *(const float4*)(cp + n);
            h[n+0] = __builtin_amdgcn_exp2f(dl * A2[n+0]) * h[n+0] + du * b4.x;
            h[n+1] = __builtin_amdgcn_exp2f(dl * A2[n+1]) * h[n+1] + du * b4.y;
            h[n+2] = __builtin_amdgcn_exp2f(dl * A2[n+2]) * h[n+2] + du * b4.z;
            h[n+3] = __builtin_amdgcn_exp2f(dl * A2[n+3]) * h[n+3] + du * b4.w;
            acc += h[n+0] * c4.x;
            acc += h[n+1] * c4.y;
            acc += h[n+2] * c4.z;
            acc += h[n+3] * c4.w;
        }
        yp[(size_t)t * DMODEL] = acc;
    }
}

template<int NC>
static void launch_chunked(const float* u, const float* de, const float* A,
                           const float* Bm, const float* Cm, const float* Dv,
                           float* ws_h, float* ws_d, float* y, hipStream_t stream) {
    dim3 grid(DMODEL / BLOCK, NC, BATCH);
    ssm_phaseA<NC><<<grid, BLOCK, 0, stream>>>(u, de, A, Bm, ws_h, ws_d);
    dim3 gridB((BATCH * DSTATE * DMODEL) / BLOCK, 1, 1);
    ssm_phaseB<NC><<<gridB, BLOCK, 0, stream>>>(A, ws_h, ws_d);
    ssm_phaseC<NC><<<grid, BLOCK, 0, stream>>>(u, de, A, Bm, Cm, Dv, ws_h, y);
}

extern "C" void kernel_launch(void* const* d_in, const int* in_sizes, int n_in,
                              void* d_out, int out_size, void* d_ws, size_t ws_size,
                              hipStream_t stream) {
    const float* u  = (const float*)d_in[0];
    const float* de = (const float*)d_in[1];
    const float* A  = (const float*)d_in[2];
    const float* Bm = (const float*)d_in[3];
    const float* Cm = (const float*)d_in[4];
    const float* Dv = (const float*)d_in[5];
    float* y = (float*)d_out;

    auto need = [](int nc) {
        return ((size_t)BATCH * nc * DSTATE * DMODEL +
                (size_t)BATCH * nc * DMODEL) * sizeof(float);
    };

    if (ws_size >= need(64)) {
        float* ws_h = (float*)d_ws;
        float* ws_d = ws_h + (size_t)BATCH * 64 * DSTATE * DMODEL;
        launch_chunked<64>(u, de, A, Bm, Cm, Dv, ws_h, ws_d, y, stream);
    } else if (ws_size >= need(16)) {
        float* ws_h = (float*)d_ws;
        float* ws_d = ws_h + (size_t)BATCH * 16 * DSTATE * DMODEL;
        launch_chunked<16>(u, de, A, Bm, Cm, Dv, ws_h, ws_d, y, stream);
    } else {
        dim3 grid(DMODEL / BLOCK, 1, BATCH);
        ssm_naive<<<grid, BLOCK, 0, stream>>>(u, de, A, Bm, Cm, Dv, y);
    }
}

// Round 3
// 114.294 us; speedup vs baseline: 1.2279x; 1.0182x over previous
//
#include <hip/hip_runtime.h>

#define BATCH   8
#define SEQLEN  2048
#define DMODEL  1024
#define DSTATE  16
#define BLOCK   256
#define COLS    2                      // d-columns per thread (float2 path)
#define LOG2E   1.4426950408889634f

// ---------------------------------------------------------------------------
// Phase A: per-(b,d,chunk) local scan from h=0. Each thread owns 2 adjacent
// d columns (float2 loads, explicit 1-ahead prefetch). Emits h_loc + dsum.
// ---------------------------------------------------------------------------
template<int NC>
__global__ __launch_bounds__(BLOCK) void ssm_phaseA(
    const float* __restrict__ u,  const float* __restrict__ de,
    const float* __restrict__ A,  const float* __restrict__ Bm,
    float* __restrict__ ws_h, float* __restrict__ ws_d)
{
    constexpr int TC = SEQLEN / NC;
    __shared__ float sB[TC * DSTATE];
    const int tid = threadIdx.x;
    const int d0  = (blockIdx.x * BLOCK + tid) * COLS;
    const int c   = blockIdx.y;
    const int b   = blockIdx.z;
    const int t0  = c * TC;

    {   // stage B tile (broadcast data), coalesced
        const float4* src = (const float4*)(Bm + (size_t)(b * SEQLEN + t0) * DSTATE);
        float4* dst = (float4*)sB;
        for (int i = tid; i < TC * DSTATE / 4; i += BLOCK)
            dst[i] = src[i];
    }
    __syncthreads();

    float A2[COLS][DSTATE];
    #pragma unroll
    for (int i = 0; i < COLS; ++i)
        #pragma unroll
        for (int n = 0; n < DSTATE; n += 4) {
            float4 a4 = *(const float4*)(A + (size_t)(d0 + i) * DSTATE + n);
            A2[i][n+0] = a4.x * LOG2E; A2[i][n+1] = a4.y * LOG2E;
            A2[i][n+2] = a4.z * LOG2E; A2[i][n+3] = a4.w * LOG2E;
        }

    float h[COLS][DSTATE];
    #pragma unroll
    for (int i = 0; i < COLS; ++i)
        #pragma unroll
        for (int n = 0; n < DSTATE; ++n) h[i][n] = 0.f;
    float dsum[COLS] = {0.f, 0.f};

    const float2* up = (const float2*)(u  + (size_t)(b * SEQLEN + t0) * DMODEL + d0);
    const float2* dp = (const float2*)(de + (size_t)(b * SEQLEN + t0) * DMODEL + d0);
    constexpr int STRIDE2 = DMODEL / 2;

    float2 uc = up[0], dc = dp[0];
    #pragma unroll 2
    for (int t = 0; t < TC; ++t) {
        float2 un, dn;
        if (t + 1 < TC) { un = up[(size_t)(t+1) * STRIDE2]; dn = dp[(size_t)(t+1) * STRIDE2]; }
        const float dl[COLS] = {dc.x, dc.y};
        const float du[COLS] = {dc.x * uc.x, dc.y * uc.y};
        dsum[0] += dc.x; dsum[1] += dc.y;
        #pragma unroll
        for (int n = 0; n < DSTATE; n += 4) {
            float4 b4 = *(const float4*)(sB + t * DSTATE + n);
            #pragma unroll
            for (int i = 0; i < COLS; ++i) {
                h[i][n+0] = __builtin_amdgcn_exp2f(dl[i] * A2[i][n+0]) * h[i][n+0] + du[i] * b4.x;
                h[i][n+1] = __builtin_amdgcn_exp2f(dl[i] * A2[i][n+1]) * h[i][n+1] + du[i] * b4.y;
                h[i][n+2] = __builtin_amdgcn_exp2f(dl[i] * A2[i][n+2]) * h[i][n+2] + du[i] * b4.z;
                h[i][n+3] = __builtin_amdgcn_exp2f(dl[i] * A2[i][n+3]) * h[i][n+3] + du[i] * b4.w;
            }
        }
        uc = un; dc = dn;
    }

    float* wh = ws_h + (size_t)(b * NC + c) * DSTATE * DMODEL + d0;
    #pragma unroll
    for (int n = 0; n < DSTATE; ++n)
        *(float2*)(wh + (size_t)n * DMODEL) = make_float2(h[0][n], h[1][n]);
    *(float2*)(ws_d + (size_t)(b * NC + c) * DMODEL + d0) = make_float2(dsum[0], dsum[1]);
}

// ---------------------------------------------------------------------------
// Phase B: inter-chunk exclusive prefix scan, in place. One thread per
// (b,n,d) strand.
// ---------------------------------------------------------------------------
template<int NC>
__global__ __launch_bounds__(BLOCK) void ssm_phaseB(
    const float* __restrict__ A,
    float* __restrict__ ws_h, const float* __restrict__ ws_d)
{
    const int gid = blockIdx.x * BLOCK + threadIdx.x;   // (b, n, d)
    const int d  = gid % DMODEL;
    const int bn = gid / DMODEL;
    const int n  = bn % DSTATE;
    const int b  = bn / DSTATE;

    const float a2 = A[(size_t)d * DSTATE + n] * LOG2E;
    float h = 0.f;
    size_t ih = (size_t)b * NC * DSTATE * DMODEL + (size_t)n * DMODEL + d;
    size_t id = (size_t)b * NC * DMODEL + d;

    #pragma unroll 4
    for (int c = 0; c < NC; ++c) {
        float hl = ws_h[ih];
        float ds = ws_d[id];
        ws_h[ih] = h;                       // exclusive prefix
        h = __builtin_amdgcn_exp2f(a2 * ds) * h + hl;
        ih += (size_t)DSTATE * DMODEL;
        id += DMODEL;
    }
}

// ---------------------------------------------------------------------------
// Phase C: load incoming state, re-scan chunk, write y. 2 cols/thread.
// ---------------------------------------------------------------------------
template<int NC>
__global__ __launch_bounds__(BLOCK) void ssm_phaseC(
    const float* __restrict__ u,  const float* __restrict__ de,
    const float* __restrict__ A,  const float* __restrict__ Bm,
    const float* __restrict__ Cm, const float* __restrict__ Dv,
    const float* __restrict__ ws_h, float* __restrict__ y)
{
    constexpr int TC = SEQLEN / NC;
    __shared__ float sB[TC * DSTATE];
    __shared__ float sC[TC * DSTATE];
    const int tid = threadIdx.x;
    const int d0  = (blockIdx.x * BLOCK + tid) * COLS;
    const int c   = blockIdx.y;
    const int b   = blockIdx.z;
    const int t0  = c * TC;

    {
        const float4* srcB = (const float4*)(Bm + (size_t)(b * SEQLEN + t0) * DSTATE);
        const float4* srcC = (const float4*)(Cm + (size_t)(b * SEQLEN + t0) * DSTATE);
        float4* dstB = (float4*)sB;
        float4* dstC = (float4*)sC;
        for (int i = tid; i < TC * DSTATE / 4; i += BLOCK) {
            dstB[i] = srcB[i];
            dstC[i] = srcC[i];
        }
    }
    __syncthreads();

    float A2[COLS][DSTATE];
    #pragma unroll
    for (int i = 0; i < COLS; ++i)
        #pragma unroll
        for (int n = 0; n < DSTATE; n += 4) {
            float4 a4 = *(const float4*)(A + (size_t)(d0 + i) * DSTATE + n);
            A2[i][n+0] = a4.x * LOG2E; A2[i][n+1] = a4.y * LOG2E;
            A2[i][n+2] = a4.z * LOG2E; A2[i][n+3] = a4.w * LOG2E;
        }

    // incoming state from phase B (coalesced float2)
    float h[COLS][DSTATE];
    {
        const float* wh = ws_h + (size_t)(b * NC + c) * DSTATE * DMODEL + d0;
        #pragma unroll
        for (int n = 0; n < DSTATE; ++n) {
            float2 hv = *(const float2*)(wh + (size_t)n * DMODEL);
            h[0][n] = hv.x; h[1][n] = hv.y;
        }
    }

    const float2 Dd = *(const float2*)(Dv + d0);
    const float2* up = (const float2*)(u  + (size_t)(b * SEQLEN + t0) * DMODEL + d0);
    const float2* dp = (const float2*)(de + (size_t)(b * SEQLEN + t0) * DMODEL + d0);
    float2* yp = (float2*)(y + (size_t)(b * SEQLEN + t0) * DMODEL + d0);
    constexpr int STRIDE2 = DMODEL / 2;

    float2 uc = up[0], dc = dp[0];
    #pragma unroll 2
    for (int t = 0; t < TC; ++t) {
        float2 un, dn;
        if (t + 1 < TC) { un = up[(size_t)(t+1) * STRIDE2]; dn = dp[(size_t)(t+1) * STRIDE2]; }
        const float dl[COLS] = {dc.x, dc.y};
        const float du[COLS] = {dc.x * uc.x, dc.y * uc.y};
        float acc[COLS] = {Dd.x * uc.x, Dd.y * uc.y};
        #pragma unroll
        for (int n = 0; n < DSTATE; n += 4) {
            float4 b4 = *(const float4*)(sB + t * DSTATE + n);
            float4 c4 = *(const float4*)(sC + t * DSTATE + n);
            #pragma unroll
            for (int i = 0; i < COLS; ++i) {
                h[i][n+0] = __builtin_amdgcn_exp2f(dl[i] * A2[i][n+0]) * h[i][n+0] + du[i] * b4.x;
                h[i][n+1] = __builtin_amdgcn_exp2f(dl[i] * A2[i][n+1]) * h[i][n+1] + du[i] * b4.y;
                h[i][n+2] = __builtin_amdgcn_exp2f(dl[i] * A2[i][n+2]) * h[i][n+2] + du[i] * b4.z;
                h[i][n+3] = __builtin_amdgcn_exp2f(dl[i] * A2[i][n+3]) * h[i][n+3] + du[i] * b4.w;
                acc[i] += h[i][n+0] * c4.x;
                acc[i] += h[i][n+1] * c4.y;
                acc[i] += h[i][n+2] * c4.z;
                acc[i] += h[i][n+3] * c4.w;
            }
        }
        yp[(size_t)t * STRIDE2] = make_float2(acc[0], acc[1]);
        uc = un; dc = dn;
    }
}

// ---------------------------------------------------------------------------
// Fallback: 1 thread per (b,d), full sequential scan. Correct but slow.
// ---------------------------------------------------------------------------
__global__ __launch_bounds__(BLOCK) void ssm_naive(
    const float* __restrict__ u,  const float* __restrict__ de,
    const float* __restrict__ A,  const float* __restrict__ Bm,
    const float* __restrict__ Cm, const float* __restrict__ Dv,
    float* __restrict__ y)
{
    const int tid = threadIdx.x;
    const int d   = blockIdx.x * BLOCK + tid;
    const int b   = blockIdx.z;

    float A2[DSTATE];
    #pragma unroll
    for (int n = 0; n < DSTATE; n += 4) {
        float4 a4 = *(const float4*)(A + (size_t)d * DSTATE + n);
        A2[n+0] = a4.x * LOG2E; A2[n+1] = a4.y * LOG2E;
        A2[n+2] = a4.z * LOG2E; A2[n+3] = a4.w * LOG2E;
    }
    float h[DSTATE];
    #pragma unroll
    for (int n = 0; n < DSTATE; ++n) h[n] = 0.f;
    const float Dd = Dv[d];

    const float* up = u  + (size_t)b * SEQLEN * DMODEL + d;
    const float* dp = de + (size_t)b * SEQLEN * DMODEL + d;
    float* yp = y + (size_t)b * SEQLEN * DMODEL + d;

    for (int t = 0; t < SEQLEN; ++t) {
        float dl = dp[(size_t)t * DMODEL];
        float uu = up[(size_t)t * DMODEL];
        float du  = dl * uu;
        float acc = Dd * uu;
        const float* bp = Bm + (size_t)(b * SEQLEN + t) * DSTATE;
        const float* cp = Cm + (size_t)(b * SEQLEN + t) * DSTATE;
        #pragma unroll
        for (int n = 0; n < DSTATE; n += 4) {
            float4 b4 = *(const float4*)(bp + n);
            float4 c4 = *(const float4*)(cp + n);
            h[n+0] = __builtin_amdgcn_exp2f(dl * A2[n+0]) * h[n+0] + du * b4.x;
            h[n+1] = __builtin_amdgcn_exp2f(dl * A2[n+1]) * h[n+1] + du * b4.y;
            h[n+2] = __builtin_amdgcn_exp2f(dl * A2[n+2]) * h[n+2] + du * b4.z;
            h[n+3] = __builtin_amdgcn_exp2f(dl * A2[n+3]) * h[n+3] + du * b4.w;
            acc += h[n+0] * c4.x;
            acc += h[n+1] * c4.y;
            acc += h[n+2] * c4.z;
            acc += h[n+3] * c4.w;
        }
        yp[(size_t)t * DMODEL] = acc;
    }
}

template<int NC>
static void launch_chunked(const float* u, const float* de, const float* A,
                           const float* Bm, const float* Cm, const float* Dv,
                           float* ws_h, float* ws_d, float* y, hipStream_t stream) {
    dim3 grid(DMODEL / (BLOCK * COLS), NC, BATCH);
    ssm_phaseA<NC><<<grid, BLOCK, 0, stream>>>(u, de, A, Bm, ws_h, ws_d);
    dim3 gridB((BATCH * DSTATE * DMODEL) / BLOCK, 1, 1);
    ssm_phaseB<NC><<<gridB, BLOCK, 0, stream>>>(A, ws_h, ws_d);
    ssm_phaseC<NC><<<grid, BLOCK, 0, stream>>>(u, de, A, Bm, Cm, Dv, ws_h, y);
}

extern "C" void kernel_launch(void* const* d_in, const int* in_sizes, int n_in,
                              void* d_out, int out_size, void* d_ws, size_t ws_size,
                              hipStream_t stream) {
    const float* u  = (const float*)d_in[0];
    const float* de = (const float*)d_in[1];
    const float* A  = (const float*)d_in[2];
    const float* Bm = (const float*)d_in[3];
    const float* Cm = (const float*)d_in[4];
    const float* Dv = (const float*)d_in[5];
    float* y = (float*)d_out;

    auto need = [](int nc) {
        return ((size_t)BATCH * nc * DSTATE * DMODEL +
                (size_t)BATCH * nc * DMODEL) * sizeof(float);
    };

    if (ws_size >= need(64)) {
        float* ws_h = (float*)d_ws;
        float* ws_d = ws_h + (size_t)BATCH * 64 * DSTATE * DMODEL;
        launch_chunked<64>(u, de, A, Bm, Cm, Dv, ws_h, ws_d, y, stream);
    } else if (ws_size >= need(16)) {
        float* ws_h = (float*)d_ws;
        float* ws_d = ws_h + (size_t)BATCH * 16 * DSTATE * DMODEL;
        launch_chunked<16>(u, de, A, Bm, Cm, Dv, ws_h, ws_d, y, stream);
    } else {
        dim3 grid(DMODEL / BLOCK, 1, BATCH);
        ssm_naive<<<grid, BLOCK, 0, stream>>>(u, de, A, Bm, Cm, Dv, y);
    }
}

// Round 4
// 113.935 us; speedup vs baseline: 1.2317x; 1.0031x over previous
//
#include <hip/hip_runtime.h>

#define BATCH   8
#define SEQLEN  2048
#define DMODEL  1024
#define DSTATE  16
#define BLOCK   256
#define LOG2E   1.4426950408889634f

// ---------------------------------------------------------------------------
// Phase A: per-(b,d,chunk) local scan from h=0, COLS=1, depth-2 prefetch,
// B rows read via wave-uniform addresses (scalar loads). Emits h_loc + dsum.
// ---------------------------------------------------------------------------
template<int NC>
__global__ __launch_bounds__(BLOCK, 8) void ssm_phaseA(
    const float* __restrict__ u,  const float* __restrict__ de,
    const float* __restrict__ A,  const float* __restrict__ Bm,
    float* __restrict__ ws_h, float* __restrict__ ws_d)
{
    constexpr int TC = SEQLEN / NC;
    const int tid = threadIdx.x;
    const int d   = blockIdx.x * BLOCK + tid;
    const int c   = blockIdx.y;
    const int b   = blockIdx.z;
    const int t0  = c * TC;

    float A2[DSTATE];
    #pragma unroll
    for (int n = 0; n < DSTATE; n += 4) {
        float4 a4 = *(const float4*)(A + (size_t)d * DSTATE + n);
        A2[n+0] = a4.x * LOG2E; A2[n+1] = a4.y * LOG2E;
        A2[n+2] = a4.z * LOG2E; A2[n+3] = a4.w * LOG2E;
    }
    float h[DSTATE];
    #pragma unroll
    for (int n = 0; n < DSTATE; ++n) h[n] = 0.f;
    float dsum = 0.f;

    const float* up = u  + (size_t)(b * SEQLEN + t0) * DMODEL + d;
    const float* dp = de + (size_t)(b * SEQLEN + t0) * DMODEL + d;
    const float* brow = Bm + (size_t)(b * SEQLEN + t0) * DSTATE;   // wave-uniform

    // depth-2 register prefetch of u/delta
    float u0 = up[0], d0 = dp[0];
    float u1 = up[DMODEL], d1 = dp[DMODEL];

    for (int t = 0; t < TC; t += 2) {
        const int i2 = (t + 2 < TC) ? (t + 2) : (TC - 1);
        const int i3 = (t + 3 < TC) ? (t + 3) : (TC - 1);
        float u2 = up[(size_t)i2 * DMODEL], d2 = dp[(size_t)i2 * DMODEL];
        float u3 = up[(size_t)i3 * DMODEL], d3 = dp[(size_t)i3 * DMODEL];

        {
            dsum += d0;
            const float du = d0 * u0;
            #pragma unroll
            for (int n = 0; n < DSTATE; n += 4) {
                float4 b4 = *(const float4*)(brow + (size_t)t * DSTATE + n);
                h[n+0] = __builtin_amdgcn_exp2f(d0 * A2[n+0]) * h[n+0] + du * b4.x;
                h[n+1] = __builtin_amdgcn_exp2f(d0 * A2[n+1]) * h[n+1] + du * b4.y;
                h[n+2] = __builtin_amdgcn_exp2f(d0 * A2[n+2]) * h[n+2] + du * b4.z;
                h[n+3] = __builtin_amdgcn_exp2f(d0 * A2[n+3]) * h[n+3] + du * b4.w;
            }
        }
        {
            dsum += d1;
            const float du = d1 * u1;
            #pragma unroll
            for (int n = 0; n < DSTATE; n += 4) {
                float4 b4 = *(const float4*)(brow + (size_t)(t+1) * DSTATE + n);
                h[n+0] = __builtin_amdgcn_exp2f(d1 * A2[n+0]) * h[n+0] + du * b4.x;
                h[n+1] = __builtin_amdgcn_exp2f(d1 * A2[n+1]) * h[n+1] + du * b4.y;
                h[n+2] = __builtin_amdgcn_exp2f(d1 * A2[n+2]) * h[n+2] + du * b4.z;
                h[n+3] = __builtin_amdgcn_exp2f(d1 * A2[n+3]) * h[n+3] + du * b4.w;
            }
        }
        u0 = u2; d0 = d2; u1 = u3; d1 = d3;
    }

    float* wh = ws_h + (size_t)(b * NC + c) * DSTATE * DMODEL + d;
    #pragma unroll
    for (int n = 0; n < DSTATE; ++n) wh[(size_t)n * DMODEL] = h[n];
    ws_d[(size_t)(b * NC + c) * DMODEL + d] = dsum;
}

// ---------------------------------------------------------------------------
// Phase B: inter-chunk exclusive prefix scan, in place. One thread per
// (b,n,d) strand. ws data is L3-hot (just written) -> cheap.
// ---------------------------------------------------------------------------
template<int NC>
__global__ __launch_bounds__(BLOCK) void ssm_phaseB(
    const float* __restrict__ A,
    float* __restrict__ ws_h, const float* __restrict__ ws_d)
{
    const int gid = blockIdx.x * BLOCK + threadIdx.x;   // (b, n, d)
    const int d  = gid % DMODEL;
    const int bn = gid / DMODEL;
    const int n  = bn % DSTATE;
    const int b  = bn / DSTATE;

    const float a2 = A[(size_t)d * DSTATE + n] * LOG2E;
    float h = 0.f;
    size_t ih = (size_t)b * NC * DSTATE * DMODEL + (size_t)n * DMODEL + d;
    size_t id = (size_t)b * NC * DMODEL + d;

    #pragma unroll 4
    for (int c = 0; c < NC; ++c) {
        float hl = ws_h[ih];
        float ds = ws_d[id];
        ws_h[ih] = h;                       // exclusive prefix
        h = __builtin_amdgcn_exp2f(a2 * ds) * h + hl;
        ih += (size_t)DSTATE * DMODEL;
        id += DMODEL;
    }
}

// ---------------------------------------------------------------------------
// Phase C: load incoming state, re-scan chunk, write y (non-temporal).
// ---------------------------------------------------------------------------
template<int NC>
__global__ __launch_bounds__(BLOCK, 8) void ssm_phaseC(
    const float* __restrict__ u,  const float* __restrict__ de,
    const float* __restrict__ A,  const float* __restrict__ Bm,
    const float* __restrict__ Cm, const float* __restrict__ Dv,
    const float* __restrict__ ws_h, float* __restrict__ y)
{
    constexpr int TC = SEQLEN / NC;
    const int tid = threadIdx.x;
    const int d   = blockIdx.x * BLOCK + tid;
    const int c   = blockIdx.y;
    const int b   = blockIdx.z;
    const int t0  = c * TC;

    float A2[DSTATE];
    #pragma unroll
    for (int n = 0; n < DSTATE; n += 4) {
        float4 a4 = *(const float4*)(A + (size_t)d * DSTATE + n);
        A2[n+0] = a4.x * LOG2E; A2[n+1] = a4.y * LOG2E;
        A2[n+2] = a4.z * LOG2E; A2[n+3] = a4.w * LOG2E;
    }

    float h[DSTATE];
    {
        const float* wh = ws_h + (size_t)(b * NC + c) * DSTATE * DMODEL + d;
        #pragma unroll
        for (int n = 0; n < DSTATE; ++n) h[n] = wh[(size_t)n * DMODEL];
    }

    const float Dd = Dv[d];
    const float* up = u  + (size_t)(b * SEQLEN + t0) * DMODEL + d;
    const float* dp = de + (size_t)(b * SEQLEN + t0) * DMODEL + d;
    const float* brow = Bm + (size_t)(b * SEQLEN + t0) * DSTATE;   // uniform
    const float* crow = Cm + (size_t)(b * SEQLEN + t0) * DSTATE;   // uniform
    float* yp = y + (size_t)(b * SEQLEN + t0) * DMODEL + d;

    float u0 = up[0], d0 = dp[0];
    float u1 = up[DMODEL], d1 = dp[DMODEL];

    for (int t = 0; t < TC; t += 2) {
        const int i2 = (t + 2 < TC) ? (t + 2) : (TC - 1);
        const int i3 = (t + 3 < TC) ? (t + 3) : (TC - 1);
        float u2 = up[(size_t)i2 * DMODEL], d2 = dp[(size_t)i2 * DMODEL];
        float u3 = up[(size_t)i3 * DMODEL], d3 = dp[(size_t)i3 * DMODEL];

        {
            const float du = d0 * u0;
            float acc = Dd * u0;
            #pragma unroll
            for (int n = 0; n < DSTATE; n += 4) {
                float4 b4 = *(const float4*)(brow + (size_t)t * DSTATE + n);
                float4 c4 = *(const float4*)(crow + (size_t)t * DSTATE + n);
                h[n+0] = __builtin_amdgcn_exp2f(d0 * A2[n+0]) * h[n+0] + du * b4.x;
                h[n+1] = __builtin_amdgcn_exp2f(d0 * A2[n+1]) * h[n+1] + du * b4.y;
                h[n+2] = __builtin_amdgcn_exp2f(d0 * A2[n+2]) * h[n+2] + du * b4.z;
                h[n+3] = __builtin_amdgcn_exp2f(d0 * A2[n+3]) * h[n+3] + du * b4.w;
                acc += h[n+0] * c4.x; acc += h[n+1] * c4.y;
                acc += h[n+2] * c4.z; acc += h[n+3] * c4.w;
            }
            __builtin_nontemporal_store(acc, yp + (size_t)t * DMODEL);
        }
        {
            const float du = d1 * u1;
            float acc = Dd * u1;
            #pragma unroll
            for (int n = 0; n < DSTATE; n += 4) {
                float4 b4 = *(const float4*)(brow + (size_t)(t+1) * DSTATE + n);
                float4 c4 = *(const float4*)(crow + (size_t)(t+1) * DSTATE + n);
                h[n+0] = __builtin_amdgcn_exp2f(d1 * A2[n+0]) * h[n+0] + du * b4.x;
                h[n+1] = __builtin_amdgcn_exp2f(d1 * A2[n+1]) * h[n+1] + du * b4.y;
                h[n+2] = __builtin_amdgcn_exp2f(d1 * A2[n+2]) * h[n+2] + du * b4.z;
                h[n+3] = __builtin_amdgcn_exp2f(d1 * A2[n+3]) * h[n+3] + du * b4.w;
                acc += h[n+0] * c4.x; acc += h[n+1] * c4.y;
                acc += h[n+2] * c4.z; acc += h[n+3] * c4.w;
            }
            __builtin_nontemporal_store(acc, yp + (size_t)(t+1) * DMODEL);
        }
        u0 = u2; d0 = d2; u1 = u3; d1 = d3;
    }
}

// ---------------------------------------------------------------------------
// Fallback: 1 thread per (b,d), full sequential scan. Correct but slow.
// ---------------------------------------------------------------------------
__global__ __launch_bounds__(BLOCK) void ssm_naive(
    const float* __restrict__ u,  const float* __restrict__ de,
    const float* __restrict__ A,  const float* __restrict__ Bm,
    const float* __restrict__ Cm, const float* __restrict__ Dv,
    float* __restrict__ y)
{
    const int tid = threadIdx.x;
    const int d   = blockIdx.x * BLOCK + tid;
    const int b   = blockIdx.z;

    float A2[DSTATE];
    #pragma unroll
    for (int n = 0; n < DSTATE; n += 4) {
        float4 a4 = *(const float4*)(A + (size_t)d * DSTATE + n);
        A2[n+0] = a4.x * LOG2E; A2[n+1] = a4.y * LOG2E;
        A2[n+2] = a4.z * LOG2E; A2[n+3] = a4.w * LOG2E;
    }
    float h[DSTATE];
    #pragma unroll
    for (int n = 0; n < DSTATE; ++n) h[n] = 0.f;
    const float Dd = Dv[d];

    const float* up = u  + (size_t)b * SEQLEN * DMODEL + d;
    const float* dp = de + (size_t)b * SEQLEN * DMODEL + d;
    float* yp = y + (size_t)b * SEQLEN * DMODEL + d;

    for (int t = 0; t < SEQLEN; ++t) {
        float dl = dp[(size_t)t * DMODEL];
        float uu = up[(size_t)t * DMODEL];
        float du  = dl * uu;
        float acc = Dd * uu;
        const float* bp = Bm + (size_t)(b * SEQLEN + t) * DSTATE;
        const float* cp = Cm + (size_t)(b * SEQLEN + t) * DSTATE;
        #pragma unroll
        for (int n = 0; n < DSTATE; n += 4) {
            float4 b4 = *(const float4*)(bp + n);
            float4 c4 = *(const float4*)(cp + n);
            h[n+0] = __builtin_amdgcn_exp2f(dl * A2[n+0]) * h[n+0] + du * b4.x;
            h[n+1] = __builtin_amdgcn_exp2f(dl * A2[n+1]) * h[n+1] + du * b4.y;
            h[n+2] = __builtin_amdgcn_exp2f(dl * A2[n+2]) * h[n+2] + du * b4.z;
            h[n+3] = __builtin_amdgcn_exp2f(dl * A2[n+3]) * h[n+3] + du * b4.w;
            acc += h[n+0] * c4.x;
            acc += h[n+1] * c4.y;
            acc += h[n+2] * c4.z;
            acc += h[n+3] * c4.w;
        }
        yp[(size_t)t * DMODEL] = acc;
    }
}

template<int NC>
static void launch_chunked(const float* u, const float* de, const float* A,
                           const float* Bm, const float* Cm, const float* Dv,
                           float* ws_h, float* ws_d, float* y, hipStream_t stream) {
    dim3 grid(DMODEL / BLOCK, NC, BATCH);
    ssm_phaseA<NC><<<grid, BLOCK, 0, stream>>>(u, de, A, Bm, ws_h, ws_d);
    dim3 gridB((BATCH * DSTATE * DMODEL) / BLOCK, 1, 1);
    ssm_phaseB<NC><<<gridB, BLOCK, 0, stream>>>(A, ws_h, ws_d);
    ssm_phaseC<NC><<<grid, BLOCK, 0, stream>>>(u, de, A, Bm, Cm, Dv, ws_h, y);
}

extern "C" void kernel_launch(void* const* d_in, const int* in_sizes, int n_in,
                              void* d_out, int out_size, void* d_ws, size_t ws_size,
                              hipStream_t stream) {
    const float* u  = (const float*)d_in[0];
    const float* de = (const float*)d_in[1];
    const float* A  = (const float*)d_in[2];
    const float* Bm = (const float*)d_in[3];
    const float* Cm = (const float*)d_in[4];
    const float* Dv = (const float*)d_in[5];
    float* y = (float*)d_out;

    auto need = [](int nc) {
        return ((size_t)BATCH * nc * DSTATE * DMODEL +
                (size_t)BATCH * nc * DMODEL) * sizeof(float);
    };

    if (ws_size >= need(64)) {
        float* ws_h = (float*)d_ws;
        float* ws_d = ws_h + (size_t)BATCH * 64 * DSTATE * DMODEL;
        launch_chunked<64>(u, de, A, Bm, Cm, Dv, ws_h, ws_d, y, stream);
    } else if (ws_size >= need(16)) {
        float* ws_h = (float*)d_ws;
        float* ws_d = ws_h + (size_t)BATCH * 16 * DSTATE * DMODEL;
        launch_chunked<16>(u, de, A, Bm, Cm, Dv, ws_h, ws_d, y, stream);
    } else {
        dim3 grid(DMODEL / BLOCK, 1, BATCH);
        ssm_naive<<<grid, BLOCK, 0, stream>>>(u, de, A, Bm, Cm, Dv, y);
    }
}